// Round 7
// baseline (187.484 us; speedup 1.0000x reference)
//
#include <hip/hip_runtime.h>
#include <hip/hip_bf16.h>
#include <stdint.h>

// ---------------------------------------------------------------------------
// Net_71373766525077: SNN leaky layer.
//   cur = x @ W^T   (1024x4096 @ 4096x4096 fp32; mem tol 7.92 -> bf16 MFMA)
//   scan t: reset=(mem>1); mem=0.9*mem+cur[t]-reset; spk=(mem>1)
//   out = concat(spk_rec[T][N], mem_rec[T][N]) fp32
//
// R18 -> R19: RESUBMIT of R18 unchanged (container acquisition failure, not
// a kernel verdict; full audit re-run: uniform barriers, vmcnt ledger exact,
// no aliasing, no OOB, ~240 VGPR within (512,2) budget. R15->R16 precedent:
// identical resubmission after this error string ran and passed).
// R18 rationale: fuse W fp32->bf16 cvt INTO the gemm B-staging (kills the
// ~16us W-cvt pass; cvt shrinks to x-only ~4us). B staging reg-staged:
// 4x global_load_dwordx4 fp32/thread/half, RNE cvt in VALU, 2x ds_write_b128
// to the XOR-swizzled LDS address (read side unchanged). vmcnt ledger:
// B loads at p2/p3 (p6/p7), cvt+write at p3/p4 (p7/p0). p3/p7: vmcnt(4).
// p0/p4: vmcnt(0) drain BEFORE issuing stageA. A staging (gload_lds bf16
// from xb), peel+storeQuad, scan (R14 struct): unchanged. Wb removed.
// Ledger R17: fills 81 + cvt 19 + gemm 42 + scan ~27 = 169.
// Predicted: cvt ~4, gemm ~45-47 (FETCH ~80MB), total ~156-159.
// ---------------------------------------------------------------------------

typedef __attribute__((ext_vector_type(8))) short bf16x8;
typedef __attribute__((ext_vector_type(4))) float floatx4;

#define T_STEPS 1024
#define N_IN    4096
#define N_OUT   4096

#define PH_T 128                  // timesteps per scan phase
#define NPH  (T_STEPS / PH_T)     // 8 phases
#define NB_N 16                   // neurons per scan block
#define TP   132                  // LDS t-stride (floats, 16B-aligned rows)

#define TN ((size_t)T_STEPS * N_OUT)

__device__ __forceinline__ unsigned short f2bf_rne(float f) {
    unsigned int u = __builtin_bit_cast(unsigned int, f);
    unsigned int r = 0x7FFFu + ((u >> 16) & 1u);
    return (unsigned short)((u + r) >> 16);
}

// x-only conversion (W is consumed fp32 by the gemm now).
__global__ __launch_bounds__(256) void cvt_x(const float4* __restrict__ in,
                                             ushort4* __restrict__ out, int n4) {
    int i = blockIdx.x * blockDim.x + threadIdx.x;
    if (i >= n4) return;
    float4 v = in[i];
    ushort4 o;
    o.x = f2bf_rne(v.x);
    o.y = f2bf_rne(v.y);
    o.z = f2bf_rne(v.z);
    o.w = f2bf_rne(v.w);
    out[i] = o;
}

__device__ __forceinline__ void gload16(const void* g, void* l) {
    __builtin_amdgcn_global_load_lds((const __attribute__((address_space(1))) void*)g,
                                     (__attribute__((address_space(3))) void*)l,
                                     16, 0, 0);
}

#define SB0()  __builtin_amdgcn_sched_barrier(0)
#define BARR() __builtin_amdgcn_s_barrier()

// ---------------------------------------------------------------------------
// 8-phase 256x256 GEMM, Pb[z][N][T] = (A[M][kz] * W[N][kz]^T)^T.
// A bf16 (pre-cvt), W fp32 (cvt fused into staging), Pb bf16 out.
// grid = 64*S blocks x 512 thr; z=bid>>6, m_tile=(bid>>4)&3, n_tile=bid&15.
// 8 waves 2Mx4N, per-wave C = 128x64 (acc[8][4] of 16x16 frags).
// LDS 128KB: A@[b*16384], B@[32768+b*16384], each 256 rows x 64 bf16.
// Swizzle invariant: content B[row][col] lives at slot (col>>3)^(row&7)
// within the row (16B units). A staged linearly from pre-permuted source
// (gload_lds); B written directly to swizzled addr (ds_write_b128).
// Phase schedule per iteration i (tiles t0=2i buf0, t1=2i+1 buf1):
//   p0: rd A0q0+B0q0; drain+write B1h1; st buf1.Ah0(t1)
//   p1: rd B0q1;      st buf1.Ah1(t1)
//   p2: rd A0q1;      issue B0h0 loads (t2)
//   p3: issue B0h1 loads; mfma; vmcnt(4); write B0h0; publish buf1
//   p4: rd A1q0+B1q0; drain+write B0h1; st buf0.Ah0(t2)
//   p5: rd B1q1;      st buf0.Ah1(t2)
//   p6: rd A1q1;      issue B1h0 loads (t3)
//   p7: issue B1h1 loads; mfma; vmcnt(4); write B1h0; publish buf0
// Last iteration peeled: no staging; storeQuad spread over p4..p7.
// ---------------------------------------------------------------------------
__global__ __launch_bounds__(512, 2) void gemm8(const short* __restrict__ A,
                                                const float* __restrict__ Wf,
                                                unsigned short* __restrict__ Pb,
                                                int kLen) {
    __shared__ short lds[65536];  // 128 KB

    const int tid  = threadIdx.x;
    const int lane = tid & 63;
    const int wv   = tid >> 6;          // 0..7
    const int wm   = (wv >> 2) * 128;   // M-wave offset: 0 / 128
    const int wn   = (wv & 3) * 64;     // N-wave offset: 0/64/128/192

    const int bid  = blockIdx.x;
    const int z    = bid >> 6;
    const int tile = bid & 63;
    const long bm  = (long)(tile >> 4) * 256;
    const long bn  = (long)(tile & 15) * 256;
    const int kBeg = z * kLen;
    unsigned short* __restrict__ Pz = Pb + (size_t)z * TN;
    const int NT    = kLen / 64;   // K-tiles of 64
    const int NITER = NT / 2;      // 2 K-tiles per iteration

    // A staging (bf16 gload_lds): lane covers row (lane>>3), 16B slot (lane&7);
    // source col pre-permuted so linear LDS dest ends up XOR-swizzled.
    const int srow = lane >> 3;                     // 0..7
    const int scol = ((lane & 7) ^ srow) << 3;      // inverse-swizzled col
    const short* aSrc = A + (bm + wv * 8 + srow) * (long)N_IN + kBeg + scol;
    const int ldA = wv * 512;            // + b*16384 + h*8192 + q*4096 (shorts)

    // B staging (fp32 reg-staged): thread owns (row brow, 16-col strip bcq).
    const int brow = tid >> 2;           // 0..127 within half
    const int bcq  = tid & 3;            // 16-float col group
    const float* wBase = Wf + (size_t)(bn + brow) * N_IN + kBeg + bcq * 16;
    const int bsw = brow & 7;            // write-side swizzle

    // fragment read geometry (16x16x32 MFMA), swizzle applied on read
    const int fm    = lane & 15;
    const int fko   = (lane >> 4) * 8;
    const int cbase = fko ^ ((fm & 7) << 3);

    floatx4 acc[8][4] = {};
    bf16x8 af[4][2];      // A frags of current qm: [mi][ks]
    bf16x8 bq[2][2][2];   // B frags both qn: [qn][nj][ks]
    float4 b0h0[4], b0h1[4], b1h0[4], b1h1[4];  // pending fp32 B strips

    auto loadA = [&](int b, int qm) {
#pragma unroll
        for (int mi = 0; mi < 4; ++mi)
#pragma unroll
            for (int ks = 0; ks < 2; ++ks)
                af[mi][ks] = *(const bf16x8*)(
                    lds + b * 16384 + (wm + qm * 64 + mi * 16 + fm) * 64 +
                    (cbase ^ (ks << 5)));
    };
    auto loadB = [&](int b, int qn) {
#pragma unroll
        for (int nj = 0; nj < 2; ++nj)
#pragma unroll
            for (int ks = 0; ks < 2; ++ks)
                bq[qn][nj][ks] = *(const bf16x8*)(
                    lds + 32768 + b * 16384 + (wn + qn * 32 + nj * 16 + fm) * 64 +
                    (cbase ^ (ks << 5)));
    };
    auto mfma16 = [&](int qm, int qn) {
        __builtin_amdgcn_s_setprio(1);
#pragma unroll
        for (int ks = 0; ks < 2; ++ks)
#pragma unroll
            for (int mi = 0; mi < 4; ++mi)
#pragma unroll
                for (int nj = 0; nj < 2; ++nj)
                    acc[qm * 4 + mi][qn * 2 + nj] =
                        __builtin_amdgcn_mfma_f32_16x16x32_bf16(
                            af[mi][ks], bq[qn][nj][ks],
                            acc[qm * 4 + mi][qn * 2 + nj], 0, 0, 0);
        __builtin_amdgcn_s_setprio(0);
    };
    // one A half = 128 rows x 64 bf16 = 2 gload rounds
    auto stageA = [&](int b, int h, int t) {
        const short* s = aSrc + (size_t)(h * 128) * N_IN + t * 64;
        gload16(s,                     lds + b * 16384 + h * 8192 + ldA);
        gload16(s + (size_t)64 * N_IN, lds + b * 16384 + h * 8192 + 4096 + ldA);
    };
    // B fp32 load: 16 consecutive floats (4x dwordx4) of one row
    auto gldB = [&](int h, int t, float4* r) {
        const float* s = wBase + (size_t)(h * 128) * N_IN + t * 64;
#pragma unroll
        for (int j = 0; j < 4; ++j) r[j] = *(const float4*)(s + j * 4);
    };
    // cvt 16 f32 -> 16 bf16, write 2x16B to swizzled slots
    auto cwrB = [&](int b, int h, const float4* r) {
        unsigned int w[8];
#pragma unroll
        for (int j = 0; j < 4; ++j) {
            w[2 * j]     = (unsigned int)f2bf_rne(r[j].x) |
                           ((unsigned int)f2bf_rne(r[j].y) << 16);
            w[2 * j + 1] = (unsigned int)f2bf_rne(r[j].z) |
                           ((unsigned int)f2bf_rne(r[j].w) << 16);
        }
        short* base = lds + 32768 + b * 16384 + h * 8192 + brow * 64;
        uint4 v0; v0.x = w[0]; v0.y = w[1]; v0.z = w[2]; v0.w = w[3];
        uint4 v1; v1.x = w[4]; v1.y = w[5]; v1.z = w[6]; v1.w = w[7];
        *(uint4*)(base + (((bcq * 2)     ^ bsw) * 8)) = v0;
        *(uint4*)(base + (((bcq * 2 + 1) ^ bsw) * 8)) = v1;
    };
    // C/D layout: col(n)=lane&15, row(m=t)=(lane>>4)*4+reg [m89/m91].
    const int cn = lane & 15;
    const int cm = (lane >> 4) * 4;
    auto storeQuad = [&](int qm, int qn) {
#pragma unroll
        for (int mi = 0; mi < 4; ++mi)
#pragma unroll
            for (int nj = 0; nj < 2; ++nj) {
                const floatx4 a = acc[qm * 4 + mi][qn * 2 + nj];
                unsigned int lo = (unsigned int)f2bf_rne(a[0]) |
                                  ((unsigned int)f2bf_rne(a[1]) << 16);
                unsigned int hi = (unsigned int)f2bf_rne(a[2]) |
                                  ((unsigned int)f2bf_rne(a[3]) << 16);
                uint2 v; v.x = lo; v.y = hi;
                size_t nIdx = (size_t)(bn + wn + qn * 32 + nj * 16 + cn);
                *(uint2*)(Pz + nIdx * T_STEPS +
                          (size_t)(bm + wm + qm * 64 + mi * 16 + cm)) = v;
            }
    };

    // ---- prologue: A tile0 -> buf0 (gload_lds); B tiles 0,1 reg-staged.
    // Issue order (VMEM): A0(4), B0h0(4), B0h1(4), B1h0(4), B1h1(4) = 20.
    stageA(0, 0, 0); stageA(0, 1, 0);
    gldB(0, 0, b0h0); gldB(1, 0, b0h1);
    gldB(0, 1, b1h0); gldB(1, 1, b1h1);
    asm volatile("s_waitcnt vmcnt(12)" ::: "memory"); SB0();
    cwrB(0, 0, b0h0);
    asm volatile("s_waitcnt vmcnt(8)" ::: "memory"); SB0();
    cwrB(0, 1, b0h1);
    asm volatile("s_waitcnt vmcnt(4)" ::: "memory"); SB0();
    cwrB(1, 0, b1h0);
    asm volatile("s_waitcnt lgkmcnt(0)" ::: "memory"); SB0();
    BARR();   // buf0 ready; B1h1 loads (4) stay in flight

    for (int i = 0; i < NITER - 1; ++i) {
        const int t1 = 2 * i + 1;
        const int t2 = 2 * i + 2;
        const int t3 = 2 * i + 3;

        // ---- p0: buf0 (qm0,qn0); drain+write B1h1; stage buf1 Ah0 ----
        loadA(0, 0); loadB(0, 0);
        asm volatile("s_waitcnt vmcnt(0)" ::: "memory"); SB0();
        cwrB(1, 1, b1h1);
        stageA(1, 0, t1);
        asm volatile("s_waitcnt lgkmcnt(8)" ::: "memory");
        SB0(); BARR();
        asm volatile("s_waitcnt lgkmcnt(0)" ::: "memory"); SB0();
        mfma16(0, 0);
        SB0(); BARR();

        // ---- p1: buf0 (qm0,qn1) ----
        loadB(0, 1);
        stageA(1, 1, t1);
        SB0(); BARR();
        asm volatile("s_waitcnt lgkmcnt(0)" ::: "memory"); SB0();
        mfma16(0, 1);
        SB0(); BARR();

        // ---- p2: buf0 (qm1,qn0); issue B0h0 loads ----
        loadA(0, 1);
        gldB(0, t2, b0h0);
        SB0(); BARR();
        asm volatile("s_waitcnt lgkmcnt(0)" ::: "memory"); SB0();
        mfma16(1, 0);
        SB0(); BARR();

        // ---- p3: issue B0h1; mfma; retire A stages + B0h0; publish buf1 ----
        gldB(1, t2, b0h1);
        SB0(); BARR();
        mfma16(1, 1);
        asm volatile("s_waitcnt vmcnt(4)" ::: "memory"); SB0();
        cwrB(0, 0, b0h0);
        asm volatile("s_waitcnt lgkmcnt(0)" ::: "memory");
        SB0(); BARR();

        // ---- p4: buf1 (qm0,qn0); drain+write B0h1; stage buf0 Ah0 ----
        loadA(1, 0); loadB(1, 0);
        asm volatile("s_waitcnt vmcnt(0)" ::: "memory"); SB0();
        cwrB(0, 1, b0h1);
        stageA(0, 0, t2);
        asm volatile("s_waitcnt lgkmcnt(8)" ::: "memory");
        SB0(); BARR();
        asm volatile("s_waitcnt lgkmcnt(0)" ::: "memory"); SB0();
        mfma16(0, 0);
        SB0(); BARR();

        // ---- p5: buf1 (qm0,qn1) ----
        loadB(1, 1);
        stageA(0, 1, t2);
        SB0(); BARR();
        asm volatile("s_waitcnt lgkmcnt(0)" ::: "memory"); SB0();
        mfma16(0, 1);
        SB0(); BARR();

        // ---- p6: buf1 (qm1,qn0); issue B1h0 loads ----
        loadA(1, 1);
        gldB(0, t3, b1h0);
        SB0(); BARR();
        asm volatile("s_waitcnt lgkmcnt(0)" ::: "memory"); SB0();
        mfma16(1, 0);
        SB0(); BARR();

        // ---- p7: issue B1h1; mfma; retire A stages + B1h0; publish buf0 ----
        gldB(1, t3, b1h1);
        SB0(); BARR();
        mfma16(1, 1);
        asm volatile("s_waitcnt vmcnt(4)" ::: "memory"); SB0();
        cwrB(1, 0, b1h0);
        asm volatile("s_waitcnt lgkmcnt(0)" ::: "memory");
        SB0(); BARR();
    }

    // ---- peeled last iteration: no staging; stores spread over p4..p7 ----
    {
        const int t1 = 2 * (NITER - 1) + 1;

        // p0: drain+write B1h1 (loaded prev p7); stage buf1 Ah0
        loadA(0, 0); loadB(0, 0);
        asm volatile("s_waitcnt vmcnt(0)" ::: "memory"); SB0();
        cwrB(1, 1, b1h1);
        stageA(1, 0, t1);
        asm volatile("s_waitcnt lgkmcnt(8)" ::: "memory");
        SB0(); BARR();
        asm volatile("s_waitcnt lgkmcnt(0)" ::: "memory"); SB0();
        mfma16(0, 0);
        SB0(); BARR();

        // p1
        loadB(0, 1);
        stageA(1, 1, t1);
        SB0(); BARR();
        asm volatile("s_waitcnt lgkmcnt(0)" ::: "memory"); SB0();
        mfma16(0, 1);
        SB0(); BARR();

        // p2
        loadA(0, 1);
        SB0(); BARR();
        asm volatile("s_waitcnt lgkmcnt(0)" ::: "memory"); SB0();
        mfma16(1, 0);
        SB0(); BARR();

        // p3: retire buf1 A stages before p4 reads
        SB0(); BARR();
        mfma16(1, 1);
        asm volatile("s_waitcnt vmcnt(0)" ::: "memory");
        SB0(); BARR();

        // p4: final (0,0) -> store it
        loadA(1, 0); loadB(1, 0);
        asm volatile("s_waitcnt lgkmcnt(8)" ::: "memory");
        SB0(); BARR();
        asm volatile("s_waitcnt lgkmcnt(0)" ::: "memory"); SB0();
        mfma16(0, 0);
        storeQuad(0, 0);
        SB0(); BARR();

        // p5: final (0,1)
        loadB(1, 1);
        SB0(); BARR();
        asm volatile("s_waitcnt lgkmcnt(0)" ::: "memory"); SB0();
        mfma16(0, 1);
        storeQuad(0, 1);
        SB0(); BARR();

        // p6: final (1,0)
        loadA(1, 1);
        SB0(); BARR();
        asm volatile("s_waitcnt lgkmcnt(0)" ::: "memory"); SB0();
        mfma16(1, 0);
        storeQuad(1, 0);
        SB0(); BARR();

        // p7: final (1,1)
        SB0(); BARR();
        mfma16(1, 1);
        storeQuad(1, 1);
    }
}

// Fused scan over n-major Pb[z][N][T]: 256 blocks x 512 threads; block owns
// NB_N=16 neurons for ALL t. Waves 0-6 (producers): write out phase ph-1
// spk/mem from ringMem (lane owns 4 consecutive n -> float4 stores). Threads
// 0-255 additionally stage phase ph+1: thread owns (n, 8-t chunk) -> uint4
// load per partial, f32-sum, 2x float4 ring writes. Wave 7 (consumer, lanes
// 0..15): serial recurrence ringCur -> ringMem. [R14 structure, ~27us]
template <int NPART>
__global__ __launch_bounds__(512) void scan_kernel(const unsigned short* __restrict__ Pb,
                                                   float* __restrict__ out) {
    __shared__ float ringCur[2][NB_N * TP];   // 16.9 KB
    __shared__ float ringMem[2][NB_N * TP];   // 16.9 KB

    const int tid  = threadIdx.x;
    const int wv   = tid >> 6;     // 0..7
    const int lane = tid & 63;
    const int n0   = blockIdx.x * NB_N;

    const int pn = lane & 15;   // consumer: neuron offset within block

    // staging geometry (threads 0-255)
    const int sn = tid >> 4;    // neuron 0..15
    const int sc = tid & 15;    // 8-t chunk 0..15

    float mem = 0.0f;           // consumer state (wave 7, lanes 0..15)

    auto stage = [&](int buf, size_t tb) {
        float s[8];
#pragma unroll
        for (int j = 0; j < 8; ++j) s[j] = 0.0f;
#pragma unroll
        for (int zz = 0; zz < NPART; ++zz) {
            const uint4 v = *(const uint4*)(Pb + (size_t)zz * TN +
                                            (size_t)(n0 + sn) * T_STEPS + tb + sc * 8);
            unsigned int w0 = v.x, w1 = v.y, w2 = v.z, w3 = v.w;
            s[0] += __builtin_bit_cast(float, w0 << 16);
            s[1] += __builtin_bit_cast(float, w0 & 0xFFFF0000u);
            s[2] += __builtin_bit_cast(float, w1 << 16);
            s[3] += __builtin_bit_cast(float, w1 & 0xFFFF0000u);
            s[4] += __builtin_bit_cast(float, w2 << 16);
            s[5] += __builtin_bit_cast(float, w2 & 0xFFFF0000u);
            s[6] += __builtin_bit_cast(float, w3 << 16);
            s[7] += __builtin_bit_cast(float, w3 & 0xFFFF0000u);
        }
        float4 f0; f0.x = s[0]; f0.y = s[1]; f0.z = s[2]; f0.w = s[3];
        float4 f1; f1.x = s[4]; f1.y = s[5]; f1.z = s[6]; f1.w = s[7];
        float* rc = &ringCur[buf][sn * TP + sc * 8];
        *(float4*)rc = f0;
        *(float4*)(rc + 4) = f1;
    };

    auto writeOut = [&](int buf, size_t tb) {
        const float* mr = ringMem[buf];
        for (int it = tid; it < 512; it += 448) {
            int t  = it >> 2;
            int nq = it & 3;
            float m0 = mr[(nq * 4 + 0) * TP + t];
            float m1 = mr[(nq * 4 + 1) * TP + t];
            float m2 = mr[(nq * 4 + 2) * TP + t];
            float m3 = mr[(nq * 4 + 3) * TP + t];
            float4 mv; mv.x = m0; mv.y = m1; mv.z = m2; mv.w = m3;
            float4 sv;
            sv.x = m0 > 1.0f ? 1.0f : 0.0f;
            sv.y = m1 > 1.0f ? 1.0f : 0.0f;
            sv.z = m2 > 1.0f ? 1.0f : 0.0f;
            sv.w = m3 > 1.0f ? 1.0f : 0.0f;
            size_t idx = (tb + t) * N_OUT + n0 + nq * 4;
            *(float4*)&out[idx]      = sv;
            *(float4*)&out[TN + idx] = mv;
        }
    };

    // ---- prefill: phase 0 -> ringCur[0] ----
    if (tid < 256) stage(0, 0);
    __syncthreads();

    for (int ph = 0; ph < NPH; ++ph) {
        if (wv < 7) {
            if (ph >= 1) writeOut((ph - 1) & 1, (size_t)(ph - 1) * PH_T);
            if (tid < 256 && ph + 1 < NPH)
                stage((ph + 1) & 1, (size_t)(ph + 1) * PH_T);
        } else if (lane < 16) {
            // consumer: 128 serial steps out of ringCur[ph&1]
            const float* base = &ringCur[ph & 1][pn * TP];
            float* mbase = &ringMem[ph & 1][pn * TP];
#pragma unroll
            for (int sub = 0; sub < 4; ++sub) {
                float2 buf[16];
#pragma unroll
                for (int q = 0; q < 16; ++q)
                    buf[q] = *(const float2*)&base[sub * 32 + q * 2];
#pragma unroll
                for (int q = 0; q < 16; ++q) {
                    float rst = mem > 1.0f ? 1.0f : 0.0f;
                    mem = fmaf(0.9f, mem, buf[q].x) - rst;
                    float m0 = mem;
                    rst = mem > 1.0f ? 1.0f : 0.0f;
                    mem = fmaf(0.9f, mem, buf[q].y) - rst;
                    float2 mo; mo.x = m0; mo.y = mem;
                    *(float2*)&mbase[sub * 32 + q * 2] = mo;
                }
            }
        }
        __syncthreads();
    }

    // ---- tail: write out phase NPH-1 ----
    if (wv < 7) writeOut((NPH - 1) & 1, (size_t)(NPH - 1) * PH_T);
}

extern "C" void kernel_launch(void* const* d_in, const int* in_sizes, int n_in,
                              void* d_out, int out_size, void* d_ws, size_t ws_size,
                              hipStream_t stream) {
    const float* x = (const float*)d_in[0];  // [1024][4096] fp32
    const float* W = (const float*)d_in[1];  // [4096][4096] fp32
    float* out = (float*)d_out;              // [2][1024][4096] fp32

    char* ws = (char*)d_ws;
    const size_t xbBytes = (size_t)T_STEPS * N_IN * 2;    // 8.4 MB
    const size_t PBytes  = TN * 2;                        // 8.4 MB per bf16 partial
    short* xb = (short*)ws;
    unsigned short* Pb = (unsigned short*)(ws + xbBytes);

    // Split-K: S=4 -> 256 blocks = 1/CU for the 128KB-LDS 8-phase gemm.
    int S = 1;
    if (ws_size >= xbBytes + 4 * PBytes)      S = 4;
    else if (ws_size >= xbBytes + 2 * PBytes) S = 2;

    {
        const int n4x = T_STEPS * N_IN / 4;
        cvt_x<<<(n4x + 255) / 256, 256, 0, stream>>>(
            (const float4*)x, (ushort4*)xb, n4x);
    }

    gemm8<<<64 * S, 512, 0, stream>>>(xb, W, Pb, N_IN / S);

    if (S == 4)      scan_kernel<4><<<N_OUT / NB_N, 512, 0, stream>>>(Pb, out);
    else if (S == 2) scan_kernel<2><<<N_OUT / NB_N, 512, 0, stream>>>(Pb, out);
    else             scan_kernel<1><<<N_OUT / NB_N, 512, 0, stream>>>(Pb, out);
}

// Round 8
// 169.757 us; speedup vs baseline: 1.1044x; 1.1044x over previous
//
#include <hip/hip_runtime.h>
#include <hip/hip_bf16.h>
#include <stdint.h>

// ---------------------------------------------------------------------------
// Net_71373766525077: SNN leaky layer.
//   cur = x @ W^T   (1024x4096 @ 4096x4096 fp32; mem tol 7.92 -> bf16 MFMA)
//   scan t: reset=(mem>1); mem=0.9*mem+cur[t]-reset; spk=(mem>1)
//   out = concat(spk_rec[T][N], mem_rec[T][N]) fp32
//
// R19 -> R20: REVERT to R17 (best measured 168.8us; R19's fused W-cvt gemm
// hit 79us vs predicted 45-47 -> pre-committed abort rule). R19 counters:
// MfmaUtil 16.6 + VALUBusy 14.7 (both pipes idle -> wait-bound), VGPR
// pinned at 128 despite +64 live strip regs (spill suspect). Path closed.
// One zero-risk scan tweak on top of R17: producer role split. Waves 0-3
// stage-only (global loads issue at phase start; ~700cy latency hides under
// the consumer chain instead of landing on the barrier after writeOut),
// waves 4-6 writeOut-only (192 thr x 2-3 items), wave 7 consumer. Same
// barriers/data, disjoint waves -> no correctness surface.
// Ledger: fills 81 (harness) + cvt 19 (BW floor) + gemm 42 + scan ~27.
// Predicted: gemm ~42 (FETCH ~49MB), scan resid 23-26, total ~164-169.
// If total ~169 and scan unmoved: all components at measured/structural
// floors -> declare roofline.
// ---------------------------------------------------------------------------

typedef __attribute__((ext_vector_type(8))) short bf16x8;
typedef __attribute__((ext_vector_type(4))) float floatx4;

#define T_STEPS 1024
#define N_IN    4096
#define N_OUT   4096

#define PH_T 128                  // timesteps per scan phase
#define NPH  (T_STEPS / PH_T)     // 8 phases
#define NB_N 16                   // neurons per scan block
#define TP   132                  // LDS t-stride (floats, 16B-aligned rows)

#define TN ((size_t)T_STEPS * N_OUT)

__device__ __forceinline__ unsigned short f2bf_rne(float f) {
    unsigned int u = __builtin_bit_cast(unsigned int, f);
    unsigned int r = 0x7FFFu + ((u >> 16) & 1u);
    return (unsigned short)((u + r) >> 16);
}

// One kernel converts both inputs (x then W), float4/ushort4 vectorized.
__global__ __launch_bounds__(256) void cvt2_kernel(const float4* __restrict__ inX,
                                                   ushort4* __restrict__ outX, int n4x,
                                                   const float4* __restrict__ inW,
                                                   ushort4* __restrict__ outW, int n4w) {
    int i = blockIdx.x * blockDim.x + threadIdx.x;
    const float4* in;
    ushort4* out;
    int k;
    if (i < n4x) { in = inX; out = outX; k = i; }
    else         { in = inW; out = outW; k = i - n4x; if (k >= n4w) return; }
    float4 v = in[k];
    ushort4 o;
    o.x = f2bf_rne(v.x);
    o.y = f2bf_rne(v.y);
    o.z = f2bf_rne(v.z);
    o.w = f2bf_rne(v.w);
    out[k] = o;
}

__device__ __forceinline__ void gload16(const void* g, void* l) {
    __builtin_amdgcn_global_load_lds((const __attribute__((address_space(1))) void*)g,
                                     (__attribute__((address_space(3))) void*)l,
                                     16, 0, 0);
}

#define SB0()  __builtin_amdgcn_sched_barrier(0)
#define BARR() __builtin_amdgcn_s_barrier()

// ---------------------------------------------------------------------------
// 8-phase 256x256 GEMM, Pb[z][N][T] = (A[M][kz] * B[N][kz]^T)^T, bf16 in/out.
// grid = 64*S blocks x 512 thr; z = bid>>6, m_tile = (bid>>4)&3, n_tile=bid&15.
// 8 waves 2Mx4N, per-wave C = 128x64 (acc[8][4] of 16x16 frags).
// LDS 128KB: A@[b*16384], B@[32768+b*16384], each 256 rows x 64 bf16.
// Swizzled element layout: LDS(row, col ^ ((row&7)<<3)); staged via linear
// global_load_lds with source col pre-permuted ((lane&7)^(lane>>3))<<3.
// Phase schedule per iteration i (tiles t0=2i from buf0, t1=2i+1 from buf1):
//   p0: rd A0q0+B0q0, st buf1.Ah0(t1)   p4: rd A1q0+B1q0, st buf0.Ah0(t2)
//   p1: rd B0q1,      st buf1.Ah1(t1)   p5: rd B1q1,      st buf0.Ah1(t2)
//   p2: rd A0q1,      st buf0.Bh0(t2)   p6: rd A1q1,      st buf1.Bh0(t3)
//   p3: -,            st buf0.Bh1(t2)   p7: -,            st buf1.Bh1(t3)
//   vmcnt(4) at end of p3 (retires buf1 A+prev B) and p7 (retires buf0 A+B).
// Last iteration peeled: no prefetch; quadrant (qm,qn) stored right after
// its final mfma16 at p4..p7 (8 uint2 stores/thread per phase) to overlap
// the Pb store burst with the tail MFMA phases.  [R17 exact, 42.0us]
// ---------------------------------------------------------------------------
__global__ __launch_bounds__(512, 2) void gemm8(const short* __restrict__ A,
                                                const short* __restrict__ B,
                                                unsigned short* __restrict__ Pb,
                                                int kLen) {
    __shared__ short lds[65536];  // 128 KB

    const int tid  = threadIdx.x;
    const int lane = tid & 63;
    const int wv   = tid >> 6;          // 0..7
    const int wm   = (wv >> 2) * 128;   // M-wave offset: 0 / 128
    const int wn   = (wv & 3) * 64;     // N-wave offset: 0/64/128/192

    const int bid  = blockIdx.x;
    const int z    = bid >> 6;
    const int tile = bid & 63;
    const long bm  = (long)(tile >> 4) * 256;
    const long bn  = (long)(tile & 15) * 256;
    const int kBeg = z * kLen;
    unsigned short* __restrict__ Pz = Pb + (size_t)z * TN;
    const int NT    = kLen / 64;   // K-tiles of 64
    const int NITER = NT / 2;      // 2 K-tiles per iteration

    // staging source geometry: lane covers row (lane>>3), 16B slot (lane&7);
    // source col block pre-permuted so linear LDS ends up XOR-swizzled.
    const int srow = lane >> 3;                     // 0..7
    const int scol = ((lane & 7) ^ srow) << 3;      // inverse-swizzled col
    const short* aSrc = A + (bm + wv * 8 + srow) * (long)N_IN + kBeg + scol;
    const short* bSrc = B + (bn + wv * 8 + srow) * (long)N_IN + kBeg + scol;
    const int ldA = wv * 512;            // + b*16384 + h*8192 + q*4096 (shorts)
    const int ldB = 32768 + wv * 512;

    // fragment read geometry (16x16x32 MFMA), swizzle applied on read
    const int fm    = lane & 15;
    const int fko   = (lane >> 4) * 8;
    const int cbase = fko ^ ((fm & 7) << 3);

    floatx4 acc[8][4] = {};
    bf16x8 af[4][2];      // A frags of current qm: [mi][ks]
    bf16x8 bq[2][2][2];   // B frags both qn: [qn][nj][ks]

    auto loadA = [&](int b, int qm) {
#pragma unroll
        for (int mi = 0; mi < 4; ++mi)
#pragma unroll
            for (int ks = 0; ks < 2; ++ks)
                af[mi][ks] = *(const bf16x8*)(
                    lds + b * 16384 + (wm + qm * 64 + mi * 16 + fm) * 64 +
                    (cbase ^ (ks << 5)));
    };
    auto loadB = [&](int b, int qn) {
#pragma unroll
        for (int nj = 0; nj < 2; ++nj)
#pragma unroll
            for (int ks = 0; ks < 2; ++ks)
                bq[qn][nj][ks] = *(const bf16x8*)(
                    lds + 32768 + b * 16384 + (wn + qn * 32 + nj * 16 + fm) * 64 +
                    (cbase ^ (ks << 5)));
    };
    auto mfma16 = [&](int qm, int qn) {
        __builtin_amdgcn_s_setprio(1);
#pragma unroll
        for (int ks = 0; ks < 2; ++ks)
#pragma unroll
            for (int mi = 0; mi < 4; ++mi)
#pragma unroll
                for (int nj = 0; nj < 2; ++nj)
                    acc[qm * 4 + mi][qn * 2 + nj] =
                        __builtin_amdgcn_mfma_f32_16x16x32_bf16(
                            af[mi][ks], bq[qn][nj][ks],
                            acc[qm * 4 + mi][qn * 2 + nj], 0, 0, 0);
        __builtin_amdgcn_s_setprio(0);
    };
    // one half-operand = 128 rows x 64 bf16 = 2 gload rounds (q=0,1)
    auto stageA = [&](int b, int h, int t) {
        const short* s = aSrc + (size_t)(h * 128) * N_IN + t * 64;
        gload16(s,                     lds + b * 16384 + h * 8192 + ldA);
        gload16(s + (size_t)64 * N_IN, lds + b * 16384 + h * 8192 + 4096 + ldA);
    };
    auto stageB = [&](int b, int h, int t) {
        const short* s = bSrc + (size_t)(h * 128) * N_IN + t * 64;
        gload16(s,                     lds + b * 16384 + h * 8192 + ldB);
        gload16(s + (size_t)64 * N_IN, lds + b * 16384 + h * 8192 + 4096 + ldB);
    };
    // C/D layout: col(n)=lane&15, row(m=t)=(lane>>4)*4+reg [m89/m91].
    // n-major Pb: 4 regs = 4 consecutive t -> one dwordx2 store per frag.
    const int cn = lane & 15;
    const int cm = (lane >> 4) * 4;
    auto storeQuad = [&](int qm, int qn) {
#pragma unroll
        for (int mi = 0; mi < 4; ++mi)
#pragma unroll
            for (int nj = 0; nj < 2; ++nj) {
                const floatx4 a = acc[qm * 4 + mi][qn * 2 + nj];
                unsigned int lo = (unsigned int)f2bf_rne(a[0]) |
                                  ((unsigned int)f2bf_rne(a[1]) << 16);
                unsigned int hi = (unsigned int)f2bf_rne(a[2]) |
                                  ((unsigned int)f2bf_rne(a[3]) << 16);
                uint2 v; v.x = lo; v.y = hi;
                size_t nIdx = (size_t)(bn + wn + qn * 32 + nj * 16 + cn);
                *(uint2*)(Pz + nIdx * T_STEPS +
                          (size_t)(bm + wm + qm * 64 + mi * 16 + cm)) = v;
            }
    };

    // ---- prologue: full tile0 -> buf0, tile1 B-halves -> buf1 (12 loads) ----
    stageA(0, 0, 0); stageA(0, 1, 0);
    stageB(0, 0, 0); stageB(0, 1, 0);
    stageB(1, 0, 1); stageB(1, 1, 1);
    asm volatile("s_waitcnt vmcnt(4)" ::: "memory");  // buf0 landed; buf1.B in flight
    SB0();
    BARR();

    for (int i = 0; i < NITER - 1; ++i) {
        const int t1 = 2 * i + 1;
        const int t2 = 2 * i + 2;
        const int t3 = 2 * i + 3;

        // ---- p0: buf0 quadrant (qm0,qn0) ----
        loadA(0, 0); loadB(0, 0);
        stageA(1, 0, t1);
        asm volatile("s_waitcnt lgkmcnt(8)" ::: "memory");
        SB0(); BARR();
        asm volatile("s_waitcnt lgkmcnt(0)" ::: "memory"); SB0();
        mfma16(0, 0);
        SB0(); BARR();

        // ---- p1: buf0 (qm0,qn1) ----
        loadB(0, 1);
        stageA(1, 1, t1);
        SB0(); BARR();
        asm volatile("s_waitcnt lgkmcnt(0)" ::: "memory"); SB0();
        mfma16(0, 1);
        SB0(); BARR();

        // ---- p2: buf0 (qm1,qn0) ----
        loadA(0, 1);
        stageB(0, 0, t2);
        SB0(); BARR();
        asm volatile("s_waitcnt lgkmcnt(0)" ::: "memory"); SB0();
        mfma16(1, 0);
        SB0(); BARR();

        // ---- p3: buf0 (qm1,qn1); retire buf1 stages ----
        stageB(0, 1, t2);
        SB0(); BARR();
        mfma16(1, 1);
        asm volatile("s_waitcnt vmcnt(4)" ::: "memory");
        SB0(); BARR();

        // ---- p4: buf1 (qm0,qn0) ----
        loadA(1, 0); loadB(1, 0);
        stageA(0, 0, t2);
        asm volatile("s_waitcnt lgkmcnt(8)" ::: "memory");
        SB0(); BARR();
        asm volatile("s_waitcnt lgkmcnt(0)" ::: "memory"); SB0();
        mfma16(0, 0);
        SB0(); BARR();

        // ---- p5: buf1 (qm0,qn1) ----
        loadB(1, 1);
        stageA(0, 1, t2);
        SB0(); BARR();
        asm volatile("s_waitcnt lgkmcnt(0)" ::: "memory"); SB0();
        mfma16(0, 1);
        SB0(); BARR();

        // ---- p6: buf1 (qm1,qn0) ----
        loadA(1, 1);
        stageB(1, 0, t3);
        SB0(); BARR();
        asm volatile("s_waitcnt lgkmcnt(0)" ::: "memory"); SB0();
        mfma16(1, 0);
        SB0(); BARR();

        // ---- p7: buf1 (qm1,qn1); retire buf0 stages ----
        stageB(1, 1, t3);
        SB0(); BARR();
        mfma16(1, 1);
        asm volatile("s_waitcnt vmcnt(4)" ::: "memory");
        SB0(); BARR();
    }

    // ---- peeled last iteration: no prefetch; stores spread over p4..p7 ----
    {
        const int t1 = 2 * (NITER - 1) + 1;

        // p0
        loadA(0, 0); loadB(0, 0);
        stageA(1, 0, t1);
        asm volatile("s_waitcnt lgkmcnt(8)" ::: "memory");
        SB0(); BARR();
        asm volatile("s_waitcnt lgkmcnt(0)" ::: "memory"); SB0();
        mfma16(0, 0);
        SB0(); BARR();

        // p1
        loadB(0, 1);
        stageA(1, 1, t1);
        SB0(); BARR();
        asm volatile("s_waitcnt lgkmcnt(0)" ::: "memory"); SB0();
        mfma16(0, 1);
        SB0(); BARR();

        // p2
        loadA(0, 1);
        SB0(); BARR();
        asm volatile("s_waitcnt lgkmcnt(0)" ::: "memory"); SB0();
        mfma16(1, 0);
        SB0(); BARR();

        // p3: retire buf1 A stages before p4 reads
        SB0(); BARR();
        mfma16(1, 1);
        asm volatile("s_waitcnt vmcnt(0)" ::: "memory");
        SB0(); BARR();

        // p4: final (0,0) -> store it
        loadA(1, 0); loadB(1, 0);
        asm volatile("s_waitcnt lgkmcnt(8)" ::: "memory");
        SB0(); BARR();
        asm volatile("s_waitcnt lgkmcnt(0)" ::: "memory"); SB0();
        mfma16(0, 0);
        storeQuad(0, 0);
        SB0(); BARR();

        // p5: final (0,1)
        loadB(1, 1);
        SB0(); BARR();
        asm volatile("s_waitcnt lgkmcnt(0)" ::: "memory"); SB0();
        mfma16(0, 1);
        storeQuad(0, 1);
        SB0(); BARR();

        // p6: final (1,0)
        loadA(1, 1);
        SB0(); BARR();
        asm volatile("s_waitcnt lgkmcnt(0)" ::: "memory"); SB0();
        mfma16(1, 0);
        storeQuad(1, 0);
        SB0(); BARR();

        // p7: final (1,1)
        SB0(); BARR();
        mfma16(1, 1);
        storeQuad(1, 1);
    }
}

// Fused scan over n-major Pb[z][N][T]: 256 blocks x 512 threads; block owns
// NB_N=16 neurons for ALL t. Role split (R20): waves 0-3 stage-only (phase
// ph+1: thread owns (n, 8-t chunk) -> uint4 load per partial, f32-sum,
// 2x float4 ring writes; loads issue at phase start so HBM/L3 latency hides
// under the consumer chain). Waves 4-6 writeOut-only (phase ph-1 spk/mem
// from ringMem, float4 stores, 192 thr x 2-3 items). Wave 7 (consumer,
// lanes 0..15): serial recurrence ringCur -> ringMem.
template <int NPART>
__global__ __launch_bounds__(512) void scan_kernel(const unsigned short* __restrict__ Pb,
                                                   float* __restrict__ out) {
    __shared__ float ringCur[2][NB_N * TP];   // 16.9 KB
    __shared__ float ringMem[2][NB_N * TP];   // 16.9 KB

    const int tid  = threadIdx.x;
    const int wv   = tid >> 6;     // 0..7
    const int lane = tid & 63;
    const int n0   = blockIdx.x * NB_N;

    const int pn = lane & 15;   // consumer: neuron offset within block

    // staging geometry (threads 0-255)
    const int sn = tid >> 4;    // neuron 0..15
    const int sc = tid & 15;    // 8-t chunk 0..15

    float mem = 0.0f;           // consumer state (wave 7, lanes 0..15)

    auto stage = [&](int buf, size_t tb) {
        float s[8];
#pragma unroll
        for (int j = 0; j < 8; ++j) s[j] = 0.0f;
#pragma unroll
        for (int zz = 0; zz < NPART; ++zz) {
            const uint4 v = *(const uint4*)(Pb + (size_t)zz * TN +
                                            (size_t)(n0 + sn) * T_STEPS + tb + sc * 8);
            unsigned int w0 = v.x, w1 = v.y, w2 = v.z, w3 = v.w;
            s[0] += __builtin_bit_cast(float, w0 << 16);
            s[1] += __builtin_bit_cast(float, w0 & 0xFFFF0000u);
            s[2] += __builtin_bit_cast(float, w1 << 16);
            s[3] += __builtin_bit_cast(float, w1 & 0xFFFF0000u);
            s[4] += __builtin_bit_cast(float, w2 << 16);
            s[5] += __builtin_bit_cast(float, w2 & 0xFFFF0000u);
            s[6] += __builtin_bit_cast(float, w3 << 16);
            s[7] += __builtin_bit_cast(float, w3 & 0xFFFF0000u);
        }
        float4 f0; f0.x = s[0]; f0.y = s[1]; f0.z = s[2]; f0.w = s[3];
        float4 f1; f1.x = s[4]; f1.y = s[5]; f1.z = s[6]; f1.w = s[7];
        float* rc = &ringCur[buf][sn * TP + sc * 8];
        *(float4*)rc = f0;
        *(float4*)(rc + 4) = f1;
    };

    // writeOut on waves 4-6: threads 256..447 -> it0 = tid-256, stride 192
    auto writeOut = [&](int buf, size_t tb) {
        const float* mr = ringMem[buf];
        for (int it = tid - 256; it < 512; it += 192) {
            int t  = it >> 2;
            int nq = it & 3;
            float m0 = mr[(nq * 4 + 0) * TP + t];
            float m1 = mr[(nq * 4 + 1) * TP + t];
            float m2 = mr[(nq * 4 + 2) * TP + t];
            float m3 = mr[(nq * 4 + 3) * TP + t];
            float4 mv; mv.x = m0; mv.y = m1; mv.z = m2; mv.w = m3;
            float4 sv;
            sv.x = m0 > 1.0f ? 1.0f : 0.0f;
            sv.y = m1 > 1.0f ? 1.0f : 0.0f;
            sv.z = m2 > 1.0f ? 1.0f : 0.0f;
            sv.w = m3 > 1.0f ? 1.0f : 0.0f;
            size_t idx = (tb + t) * N_OUT + n0 + nq * 4;
            *(float4*)&out[idx]      = sv;
            *(float4*)&out[TN + idx] = mv;
        }
    };

    // ---- prefill: phase 0 -> ringCur[0] ----
    if (tid < 256) stage(0, 0);
    __syncthreads();

    for (int ph = 0; ph < NPH; ++ph) {
        if (wv < 4) {
            if (ph + 1 < NPH) stage((ph + 1) & 1, (size_t)(ph + 1) * PH_T);
        } else if (wv < 7) {
            if (ph >= 1) writeOut((ph - 1) & 1, (size_t)(ph - 1) * PH_T);
        } else if (lane < 16) {
            // consumer: 128 serial steps out of ringCur[ph&1]
            const float* base = &ringCur[ph & 1][pn * TP];
            float* mbase = &ringMem[ph & 1][pn * TP];
#pragma unroll
            for (int sub = 0; sub < 4; ++sub) {
                float2 buf[16];
#pragma unroll
                for (int q = 0; q < 16; ++q)
                    buf[q] = *(const float2*)&base[sub * 32 + q * 2];
#pragma unroll
                for (int q = 0; q < 16; ++q) {
                    float rst = mem > 1.0f ? 1.0f : 0.0f;
                    mem = fmaf(0.9f, mem, buf[q].x) - rst;
                    float m0 = mem;
                    rst = mem > 1.0f ? 1.0f : 0.0f;
                    mem = fmaf(0.9f, mem, buf[q].y) - rst;
                    float2 mo; mo.x = m0; mo.y = mem;
                    *(float2*)&mbase[sub * 32 + q * 2] = mo;
                }
            }
        }
        __syncthreads();
    }

    // ---- tail: write out phase NPH-1 (waves 4-6) ----
    if (wv >= 4 && wv < 7) writeOut((NPH - 1) & 1, (size_t)(NPH - 1) * PH_T);
}

extern "C" void kernel_launch(void* const* d_in, const int* in_sizes, int n_in,
                              void* d_out, int out_size, void* d_ws, size_t ws_size,
                              hipStream_t stream) {
    const float* x = (const float*)d_in[0];  // [1024][4096] fp32
    const float* W = (const float*)d_in[1];  // [4096][4096] fp32
    float* out = (float*)d_out;              // [2][1024][4096] fp32

    char* ws = (char*)d_ws;
    const size_t xbBytes = (size_t)T_STEPS * N_IN * 2;    // 8.4 MB
    const size_t WbBytes = (size_t)N_OUT * N_IN * 2;      // 33.6 MB
    const size_t PBytes  = TN * 2;                        // 8.4 MB per bf16 partial
    short* xb = (short*)ws;
    short* Wb = (short*)(ws + xbBytes);
    unsigned short* Pb = (unsigned short*)(ws + xbBytes + WbBytes);

    // Split-K: S=4 -> 256 blocks = 1/CU for the 128KB-LDS 8-phase gemm.
    int S = 1;
    if (ws_size >= xbBytes + WbBytes + 4 * PBytes)      S = 4;
    else if (ws_size >= xbBytes + WbBytes + 2 * PBytes) S = 2;

    {
        const int n4x = T_STEPS * N_IN / 4;
        const int n4w = N_OUT * N_IN / 4;
        const int nthr = n4x + n4w;
        cvt2_kernel<<<(nthr + 255) / 256, 256, 0, stream>>>(
            (const float4*)x, (ushort4*)xb, n4x,
            (const float4*)W, (ushort4*)Wb, n4w);
    }

    gemm8<<<64 * S, 512, 0, stream>>>(xb, Wb, Pb, N_IN / S);

    if (S == 4)      scan_kernel<4><<<N_OUT / NB_N, 512, 0, stream>>>(Pb, out);
    else if (S == 2) scan_kernel<2><<<N_OUT / NB_N, 512, 0, stream>>>(Pb, out);
    else             scan_kernel<1><<<N_OUT / NB_N, 512, 0, stream>>>(Pb, out);
}